// Round 4
// baseline (2776.055 us; speedup 1.0000x reference)
//
#include <hip/hip_runtime.h>
#include <cstdint>
#include <cstddef>

#define EE 1000000
#define NN 100000
#define NT 62500   // EE / 16 edges per wave-tile (exact, no tail)

typedef unsigned short u16;
typedef __bf16 bf16x8 __attribute__((ext_vector_type(8)));
typedef float f32x4 __attribute__((ext_vector_type(4)));

__device__ __forceinline__ u16 f2bf(float f) {
    union { float f; uint32_t u; } v; v.f = f;
    uint32_t r = v.u + 0x7FFFu + ((v.u >> 16) & 1u);   // RNE
    return (u16)(r >> 16);
}
// RNE bf16 pair pack (compiler emits v_cvt_pk_bf16_f32)
__device__ __forceinline__ uint32_t cvt2(float lo, float hi) {
    u16 a = __builtin_bit_cast(u16, (__bf16)lo);
    u16 b = __builtin_bit_cast(u16, (__bf16)hi);
    return (uint32_t)a | ((uint32_t)b << 16);
}

// ---------------- prep: pack weights into MFMA A-operand fragment streams.
// W1^T  A-frags (16x16x32): pack[((rt*12+kt)*64+lane)*8+j]
//        = W1[kt*32 + (lane>>4)*8 + j][rt*16 + (lane&15)]
// W2^T  A-frags with K-permutation d(q)=64*(j>>2)+16*kt2+4*g+(j&3) so GEMM1's
//        accumulator feeds GEMM2's B-fragment with zero cross-lane traffic:
//        pack[49152 + ((ot*4+kt2)*64+lane)*8+j]
//        = W2[64*(j>>2)+16*kt2+4*((lane>>4)&3)+(j&3)][ot*16 + (lane&15)]
// consts at pack+65536 (as f32): b1[128], b2[128], ln_g[128], ln_b[128]
__global__ void pack_weights_k(const float* __restrict__ W1, const float* __restrict__ W2,
                               const float* __restrict__ b1, const float* __restrict__ b2,
                               const float* __restrict__ lng, const float* __restrict__ lnb,
                               u16* __restrict__ pack) {
    int t = blockIdx.x * 256 + threadIdx.x;
    if (t < 49152) {
        int j = t & 7, lane = (t >> 3) & 63;
        int rem = t >> 9;          // rt*12 + kt
        int kt = rem % 12, rt = rem / 12;
        int k = kt * 32 + ((lane >> 4) & 3) * 8 + j;
        int hid = rt * 16 + (lane & 15);
        pack[t] = f2bf(W1[k * 128 + hid]);
    } else if (t < 65536) {
        int u = t - 49152;
        int j = u & 7, lane = (u >> 3) & 63;
        int kt2 = (u >> 9) & 3, ot = u >> 11;
        int hidden = 64 * (j >> 2) + 16 * kt2 + 4 * ((lane >> 4) & 3) + (j & 3);
        int outd = ot * 16 + (lane & 15);
        pack[t] = f2bf(W2[hidden * 128 + outd]);
    } else if (t < 66048) {
        int i = t - 65536;
        float v = (i < 128) ? b1[i] : (i < 256) ? b2[i - 128]
                : (i < 384) ? lng[i - 256] : lnb[i - 384];
        ((float*)(pack + 65536))[i] = v;
    }
}

// ---------------- output[1] = nfeat passthrough
__global__ void copy_nfeat_k(const float4* __restrict__ s, float4* __restrict__ d, int n) {
    for (int i = blockIdx.x * blockDim.x + threadIdx.x; i < n; i += gridDim.x * blockDim.x)
        d[i] = s[i];
}

// ---------------- main fused kernel: barrier-free per-wave tiles.
// 1024 threads = 16 waves/CU (VGPR capped at 128 by block size). Each wave
// independently owns 16 edges per tile: gathers cat^T B-fragments straight
// from global (32B/lane, rolling 4-kt window in flight), A-fragments (W1^T,
// W2^T) broadcast-read from LDS. No __syncthreads in the loop.
__global__ void __launch_bounds__(1024)
edge_mlp_k(const float* __restrict__ efeat, const float* __restrict__ nfeat,
           const int* __restrict__ srci, const int* __restrict__ dsti,
           const u16* __restrict__ pack, float* __restrict__ out) {
    extern __shared__ char smem[];
    const u16* w1 = (const u16*)smem;            // 96 KB: W1^T frags
    const u16* w2 = (const u16*)(smem + 98304);  // 32 KB: W2^T frags
    const float* cst = (const float*)(smem + 131072); // 2 KB consts

    const int tid = threadIdx.x;
    // stage weights + consts (only sync in the kernel)
    {
        const uint4* gsrc = (const uint4*)pack;   // 131072 B = 8192 uint4
        uint4* l = (uint4*)smem;
#pragma unroll
        for (int i = 0; i < 8; i++) l[tid + i * 1024] = gsrc[tid + i * 1024];
        if (tid < 512) ((float*)(smem + 131072))[tid] = ((const float*)(pack + 65536))[tid];
    }
    __syncthreads();

    const int lane = tid & 63;
    const int wid = tid >> 6;
    const int col = lane & 15;          // edge slot within tile
    const int g4 = (lane >> 4) & 3;     // k-/row-group

    const float* cb1 = cst;
    const float* cb2 = cst + 128;
    const float* cg = cst + 256;
    const float* cbb = cst + 384;

    int wt = blockIdx.x * 16 + wid;
    const int stride = (int)gridDim.x * 16;

    // tile-0 pointers + first 4 gather chunks (efeat)
    int e0 = wt * 16 + col;
    const float* rowE = efeat + (size_t)e0 * 128;
    const float* rowS = nfeat + (size_t)srci[e0] * 128;
    const float* rowD = nfeat + (size_t)dsti[e0] * 128;

    float4 blo[12], bhi[12];
#pragma unroll
    for (int kt = 0; kt < 4; kt++) {
        const float* p = rowE + kt * 32 + g4 * 8;
        blo[kt] = *(const float4*)p; bhi[kt] = *(const float4*)(p + 4);
    }

    for (; wt < NT; wt += stride) {
        // next-tile indices (issued ~a full tile before use)
        const int wtn = wt + stride;
        const int en = ((wtn < NT) ? wtn : wt) * 16 + col;
        const int sn = srci[en];
        const int dn = dsti[en];

        // ---- GEMM1: h^T[128 x 16] = W1^T · cat^T, rolling gather window
        f32x4 acc1[8] = {};
#pragma unroll
        for (int kt = 0; kt < 12; kt++) {
            if (kt < 8) {   // issue gather for kt+4 (4..7 = src row, 8..11 = dst row)
                const int kf = kt + 4;
                const float* base = (kf < 8) ? rowS : rowD;
                const float* p = base + (kf & 3) * 32 + g4 * 8;
                blo[kf] = *(const float4*)p; bhi[kf] = *(const float4*)(p + 4);
            }
            bf16x8 bf;
            {
                uint32_t* bu = (uint32_t*)&bf;
                bu[0] = cvt2(blo[kt].x, blo[kt].y);
                bu[1] = cvt2(blo[kt].z, blo[kt].w);
                bu[2] = cvt2(bhi[kt].x, bhi[kt].y);
                bu[3] = cvt2(bhi[kt].z, bhi[kt].w);
            }
#pragma unroll
            for (int rt = 0; rt < 8; rt++) {
                bf16x8 a = *(const bf16x8*)(w1 + ((rt * 12 + kt) * 64 + lane) * 8);
                acc1[rt] = __builtin_amdgcn_mfma_f32_16x16x32_bf16(a, bf, acc1[rt], 0, 0, 0);
            }
        }

        // ---- bias1 + SiLU -> packed bf16 (acc1 dies here)
        uint32_t hpk[8][2];
#pragma unroll
        for (int rt = 0; rt < 8; rt++) {
            float4 b1v = *(const float4*)(cb1 + rt * 16 + g4 * 4);
            float x0 = acc1[rt][0] + b1v.x, x1 = acc1[rt][1] + b1v.y;
            float x2 = acc1[rt][2] + b1v.z, x3 = acc1[rt][3] + b1v.w;
            float s0 = x0 / (1.f + __expf(-x0)), s1 = x1 / (1.f + __expf(-x1));
            float s2 = x2 / (1.f + __expf(-x2)), s3 = x3 / (1.f + __expf(-x3));
            hpk[rt][0] = cvt2(s0, s1);
            hpk[rt][1] = cvt2(s2, s3);
        }

        // next-tile pointers; prefetch its first 4 chunks (efeat rows)
        const float* rowEn = efeat + (size_t)en * 128;
        const float* rowSn = nfeat + (size_t)sn * 128;
        const float* rowDn = nfeat + (size_t)dn * 128;
#pragma unroll
        for (int kt = 0; kt < 4; kt++) {
            const float* p = rowEn + kt * 32 + g4 * 8;
            blo[kt] = *(const float4*)p; bhi[kt] = *(const float4*)(p + 4);
        }

        // ---- GEMM2: out^T[128 x 16] = W2^T(perm) · h^T  (B comes from hpk directly)
        f32x4 acc2[8] = {};
#pragma unroll
        for (int kt2 = 0; kt2 < 4; kt2++) {
            bf16x8 bf;
            {
                uint32_t* bu = (uint32_t*)&bf;
                bu[0] = hpk[kt2][0]; bu[1] = hpk[kt2][1];
                bu[2] = hpk[kt2 + 4][0]; bu[3] = hpk[kt2 + 4][1];
            }
#pragma unroll
            for (int ot = 0; ot < 8; ot++) {
                bf16x8 a = *(const bf16x8*)(w2 + ((ot * 4 + kt2) * 64 + lane) * 8);
                acc2[ot] = __builtin_amdgcn_mfma_f32_16x16x32_bf16(a, bf, acc2[ot], 0, 0, 0);
            }
        }

        // ---- residual loads (current tile's efeat rows: L2-hot)
        float4 ef4[8];
#pragma unroll
        for (int ot = 0; ot < 8; ot++)
            ef4[ot] = *(const float4*)(rowE + ot * 16 + g4 * 4);

        // ---- + b2, LN stats (per edge: in-lane 32 + shfl over the 4 groups)
        float s = 0.f, q = 0.f;
#pragma unroll
        for (int ot = 0; ot < 8; ot++) {
            float4 b2v = *(const float4*)(cb2 + ot * 16 + g4 * 4);
#pragma unroll
            for (int r = 0; r < 4; r++) {
                float x = acc2[ot][r] + ((const float*)&b2v)[r];
                acc2[ot][r] = x;
                s += x; q += x * x;
            }
        }
        s += __shfl_xor(s, 16); q += __shfl_xor(q, 16);
        s += __shfl_xor(s, 32); q += __shfl_xor(q, 32);
        const float mean = s * (1.f / 128.f);
        const float rstd = rsqrtf(q * (1.f / 128.f) - mean * mean + 1e-5f);

        // ---- scale/shift + residual, store (out^T frag -> row-major out)
        float* op = out + (size_t)(wt * 16 + col) * 128;
#pragma unroll
        for (int ot = 0; ot < 8; ot++) {
            float4 gv = *(const float4*)(cg + ot * 16 + g4 * 4);
            float4 bv = *(const float4*)(cbb + ot * 16 + g4 * 4);
            float4 o;
            o.x = (acc2[ot][0] - mean) * rstd * gv.x + bv.x + ef4[ot].x;
            o.y = (acc2[ot][1] - mean) * rstd * gv.y + bv.y + ef4[ot].y;
            o.z = (acc2[ot][2] - mean) * rstd * gv.z + bv.z + ef4[ot].z;
            o.w = (acc2[ot][3] - mean) * rstd * gv.w + bv.w + ef4[ot].w;
            *(float4*)(op + ot * 16 + g4 * 4) = o;
        }

        rowE = rowEn; rowS = rowSn; rowD = rowDn;
    }
}

extern "C" void kernel_launch(void* const* d_in, const int* in_sizes, int n_in,
                              void* d_out, int out_size, void* d_ws, size_t ws_size,
                              hipStream_t stream) {
    const float* efeat = (const float*)d_in[0];
    const float* nfeat = (const float*)d_in[1];
    const int* srci = (const int*)d_in[2];
    const int* dsti = (const int*)d_in[3];
    const float* W1 = (const float*)d_in[4];
    const float* b1 = (const float*)d_in[5];
    const float* W2 = (const float*)d_in[6];
    const float* b2 = (const float*)d_in[7];
    const float* lng = (const float*)d_in[8];
    const float* lnb = (const float*)d_in[9];
    float* out = (float*)d_out;

    // 130 KB pack buffer (128 KB bf16 weights + 2 KB consts); fall back to the
    // (later overwritten) nfeat output region if the workspace is too small.
    u16* pack = (ws_size >= 133120) ? (u16*)d_ws : (u16*)(out + (size_t)EE * 128);

    hipFuncSetAttribute(reinterpret_cast<const void*>(edge_mlp_k),
                        hipFuncAttributeMaxDynamicSharedMemorySize, 133120);

    pack_weights_k<<<258, 256, 0, stream>>>(W1, W2, b1, b2, lng, lnb, pack);
    edge_mlp_k<<<256, 1024, 133120, stream>>>(efeat, nfeat, srci, dsti, pack, out);
    copy_nfeat_k<<<2048, 256, 0, stream>>>((const float4*)nfeat,
                                           (float4*)(out + (size_t)EE * 128),
                                           (NN * 128) / 4);
}